// Round 1
// baseline (14780.350 us; speedup 1.0000x reference)
//
#include <hip/hip_runtime.h>
#include <hip/hip_bf16.h>
#include <stdint.h>

#define BATCH 64
#define SEQ   512
#define HID   1024
#define VOC   4096
#define LROWS (SEQ*BATCH)   // 32768 output rows

typedef __attribute__((ext_vector_type(4))) float f32x4;
typedef __attribute__((ext_vector_type(8))) short short8;

__device__ __forceinline__ unsigned short f2bf(float f) {
    unsigned int u = __builtin_bit_cast(unsigned int, f);
    u += 0x7fffu + ((u >> 16) & 1u);   // round-to-nearest-even
    return (unsigned short)(u >> 16);
}

// async global->LDS, 16B per lane, LDS dest = wave-uniform base + lane*16
#define GLL16(g, l) __builtin_amdgcn_global_load_lds( \
    (const __attribute__((address_space(1))) void*)(g), \
    (__attribute__((address_space(3))) void*)(l), 16, 0, 0)

// ---------------------------------------------------------------------------
// W_hq [1024][4096] f32  ->  Bt [4096][1024] bf16   (transpose + convert)
// ---------------------------------------------------------------------------
__global__ __launch_bounds__(256) void k_transpose_whq(
    const float* __restrict__ W, unsigned short* __restrict__ Bt)
{
    __shared__ float tile[64][65];
    const int tid = threadIdx.x;
    const int v0 = blockIdx.x * 64;
    const int k0 = blockIdx.y * 64;
    #pragma unroll
    for (int i = 0; i < 16; ++i) {
        int idx = tid + i*256;
        int r = idx >> 6, c = idx & 63;
        tile[r][c] = W[(size_t)(k0 + r)*VOC + v0 + c];
    }
    __syncthreads();
    #pragma unroll
    for (int i = 0; i < 16; ++i) {
        int idx = tid + i*256;
        int r = idx >> 6, c = idx & 63;
        Bt[(size_t)(v0 + r)*HID + k0 + c] = f2bf(tile[c][r]);
    }
}

__global__ void k_copy_f32(const float* __restrict__ src, float* __restrict__ dst, int n) {
    int i = blockIdx.x*256 + threadIdx.x;
    if (i < n) dst[i] = src[i];
}

// ---------------------------------------------------------------------------
// One recurrence step (fp32 vector):
//   Hnext = tanh(W_xh[X[:,t]] + Hprev @ W_hh + b_h)
// grid 64 wgs (16 cols each), block 256: thread = (row r, 4-col group cg)
// ---------------------------------------------------------------------------
__global__ __launch_bounds__(256) void k_rnn_step(
    const float* __restrict__ Hprev,   // [64][1024]
    float*       __restrict__ Hnext,   // [64][1024]
    unsigned short* __restrict__ Hst,  // [64][1024] bf16 (state slot t)
    const float* __restrict__ Whh,     // [1024][1024]
    const float* __restrict__ bh,      // [1024]
    const float* __restrict__ Wxh,     // [4096][1024]
    const int*   __restrict__ X,       // [64][512]
    int t)
{
    __shared__ float Hs[64][65];   // pad 65: bank = (r+k)%32, conflict-free
    __shared__ float Ws[64][20];   // pad 20: 16B-aligned float4 rows
    const int tid = threadIdx.x;
    const int g = blockIdx.x;          // col tile, 16 cols
    const int r = tid & 63;
    const int cg = tid >> 6;           // 0..3
    const int cbase = g*16 + cg*4;

    float acc0 = 0.f, acc1 = 0.f, acc2 = 0.f, acc3 = 0.f;

    for (int kk = 0; kk < HID; kk += 64) {
        __syncthreads();
        #pragma unroll
        for (int i = 0; i < 16; ++i) {          // stage H chunk 64x64
            int idx = tid + i*256;
            int rr = idx >> 6, k2 = idx & 63;
            Hs[rr][k2] = Hprev[rr*HID + kk + k2];
        }
        #pragma unroll
        for (int i = 0; i < 4; ++i) {           // stage W chunk 64x16
            int idx = tid + i*256;
            int k2 = idx >> 4, c2 = idx & 15;
            Ws[k2][c2] = Whh[(size_t)(kk + k2)*HID + g*16 + c2];
        }
        __syncthreads();
        #pragma unroll 8
        for (int k = 0; k < 64; ++k) {
            float h = Hs[r][k];
            float4 w = *(const float4*)&Ws[k][cg*4];
            acc0 += h * w.x; acc1 += h * w.y; acc2 += h * w.z; acc3 += h * w.w;
        }
    }

    const int xi = X[r*SEQ + t];
    const float* xrow = Wxh + (size_t)xi*HID;
    float o0 = tanhf(acc0 + xrow[cbase+0] + bh[cbase+0]);
    float o1 = tanhf(acc1 + xrow[cbase+1] + bh[cbase+1]);
    float o2 = tanhf(acc2 + xrow[cbase+2] + bh[cbase+2]);
    float o3 = tanhf(acc3 + xrow[cbase+3] + bh[cbase+3]);
    float* hn = Hnext + r*HID + cbase;
    hn[0] = o0; hn[1] = o1; hn[2] = o2; hn[3] = o3;
    unsigned short* hs = Hst + r*HID + cbase;
    hs[0] = f2bf(o0); hs[1] = f2bf(o1); hs[2] = f2bf(o2); hs[3] = f2bf(o3);
}

// ---------------------------------------------------------------------------
// Logits GEMM: C[L][4096] = A[L][1024](bf16) * Bt[4096][1024]^T(bf16) + b_q
// 128x128 tile, BK=64, 4 waves (2x2), each wave 64x64 = 4x4 frags 16x16x32
// ---------------------------------------------------------------------------
__global__ __launch_bounds__(256) void k_gemm_logits(
    const unsigned short* __restrict__ A,   // [LROWS][1024] bf16
    const unsigned short* __restrict__ Bt,  // [4096][1024] bf16
    const float* __restrict__ bq,           // [4096]
    float* __restrict__ C)                  // [LROWS][4096]
{
    __shared__ unsigned short lA[128*64];   // row stride 64 bf16 (128B)
    __shared__ unsigned short lB[128*64];
    const int tid  = threadIdx.x;
    const int lane = tid & 63;
    const int wave = tid >> 6;
    const int wm = wave >> 1, wn = wave & 1;
    const int bm = blockIdx.x;
    const int bn = blockIdx.y;
    const int rowA0 = bm * 128;
    const int rowB0 = bn * 128;

    f32x4 acc[4][4];
    #pragma unroll
    for (int i = 0; i < 4; ++i)
        #pragma unroll
        for (int j = 0; j < 4; ++j)
            acc[i][j] = (f32x4){0.f, 0.f, 0.f, 0.f};

    for (int kt = 0; kt < HID; kt += 64) {
        __syncthreads();
        #pragma unroll
        for (int i = 0; i < 4; ++i) {
            int slot = i*256 + tid;          // 16B slots, 8 per tile row
            int row  = slot >> 3;
            int colb = (slot & 7) * 8;       // bf16 col
            const unsigned short* ga = A  + (size_t)(rowA0 + row)*HID + kt + colb;
            const unsigned short* gb = Bt + (size_t)(rowB0 + row)*HID + kt + colb;
            unsigned short* la = lA + (i*256 + (tid >> 6)*64)*8;  // wave-uniform
            unsigned short* lb = lB + (i*256 + (tid >> 6)*64)*8;
            GLL16(ga, la);
            GLL16(gb, lb);
        }
        __syncthreads();
        #pragma unroll
        for (int ks = 0; ks < 2; ++ks) {
            short8 af[4], bf[4];
            #pragma unroll
            for (int i = 0; i < 4; ++i) {
                int row = wm*64 + i*16 + (lane & 15);
                int k   = ks*32 + (lane >> 4)*8;
                af[i] = *(const short8*)&lA[row*64 + k];
            }
            #pragma unroll
            for (int j = 0; j < 4; ++j) {
                int row = wn*64 + j*16 + (lane & 15);
                int k   = ks*32 + (lane >> 4)*8;
                bf[j] = *(const short8*)&lB[row*64 + k];
            }
            #pragma unroll
            for (int i = 0; i < 4; ++i)
                #pragma unroll
                for (int j = 0; j < 4; ++j)
                    acc[i][j] = __builtin_amdgcn_mfma_f32_16x16x32_bf16(af[i], bf[j], acc[i][j], 0, 0, 0);
        }
    }

    // epilogue: D[row=(lane>>4)*4+reg][col=lane&15] per frag, + b_q
    #pragma unroll
    for (int i = 0; i < 4; ++i) {
        int rbase = rowA0 + wm*64 + i*16 + (lane >> 4)*4;
        #pragma unroll
        for (int j = 0; j < 4; ++j) {
            int c = rowB0 + wn*64 + j*16 + (lane & 15);
            float bqv = bq[c];
            #pragma unroll
            for (int reg = 0; reg < 4; ++reg)
                C[(size_t)(rbase + reg)*VOC + c] = acc[i][j][reg] + bqv;
        }
    }
}

// ---------------------------------------------------------------------------
extern "C" void kernel_launch(void* const* d_in, const int* in_sizes, int n_in,
                              void* d_out, int out_size, void* d_ws, size_t ws_size,
                              hipStream_t stream) {
    const int*   X   = (const int*)d_in[0];
    const float* H0  = (const float*)d_in[1];
    const float* Wxh = (const float*)d_in[2];
    const float* Whh = (const float*)d_in[3];
    const float* bh  = (const float*)d_in[4];
    const float* Whq = (const float*)d_in[5];
    const float* bq  = (const float*)d_in[6];
    float* out = (float*)d_out;

    // workspace layout
    char* ws = (char*)d_ws;
    float* Hpp = (float*)ws;                                   // 2 x 65536 f32 ping-pong
    unsigned short* Hst = (unsigned short*)(ws + 2*65536*sizeof(float));          // [512][64][1024] bf16
    unsigned short* Bt  = (unsigned short*)(ws + 2*65536*sizeof(float)
                                               + (size_t)LROWS*HID*2);            // [4096][1024] bf16

    k_transpose_whq<<<dim3(VOC/64, HID/64), 256, 0, stream>>>(Whq, Bt);
    k_copy_f32<<<dim3(65536/256), 256, 0, stream>>>(H0, Hpp, 65536);

    for (int t = 0; t < SEQ; ++t) {
        const float* hp = Hpp + (t & 1)*65536;
        float*       hn = Hpp + ((t + 1) & 1)*65536;
        k_rnn_step<<<dim3(64), 256, 0, stream>>>(hp, hn, Hst + (size_t)t*65536,
                                                 Whh, bh, Wxh, X, t);
    }

    k_gemm_logits<<<dim3(LROWS/128, VOC/128), 256, 0, stream>>>(Hst, Bt, bq, out);
    // H_final ended in slot (512 & 1) == 0
    k_copy_f32<<<dim3(65536/256), 256, 0, stream>>>(Hpp, out + (size_t)LROWS*VOC, 65536);
}

// Round 2
// 6887.399 us; speedup vs baseline: 2.1460x; 2.1460x over previous
//
#include <hip/hip_runtime.h>
#include <hip/hip_bf16.h>
#include <hip/hip_cooperative_groups.h>
#include <stdint.h>

namespace cg = cooperative_groups;

#define BATCH 64
#define SEQ   512
#define HID   1024
#define VOC   4096
#define LROWS (SEQ*BATCH)   // 32768 output rows
#define HN    (BATCH*HID)   // 65536 elems per H state

typedef __attribute__((ext_vector_type(4))) float f32x4;
typedef __attribute__((ext_vector_type(8))) short short8;

__device__ __forceinline__ unsigned short f2bf(float f) {
    unsigned int u = __builtin_bit_cast(unsigned int, f);
    u += 0x7fffu + ((u >> 16) & 1u);   // round-to-nearest-even
    return (unsigned short)(u >> 16);
}

// async global->LDS, 16B per lane, LDS dest = wave-uniform base + lane*16
#define GLL16(g, l) __builtin_amdgcn_global_load_lds( \
    (const __attribute__((address_space(1))) void*)(g), \
    (__attribute__((address_space(3))) void*)(l), 16, 0, 0)

// ---------------------------------------------------------------------------
// Generic: in[R][C] f32  ->  out[C][R] bf16   (transpose + convert)
// grid (C/64, R/64), block 256
// ---------------------------------------------------------------------------
__global__ __launch_bounds__(256) void k_transpose_f32_bf16(
    const float* __restrict__ in, unsigned short* __restrict__ out, int R, int C)
{
    __shared__ float tile[64][65];
    const int tid = threadIdx.x;
    const int c0 = blockIdx.x * 64;
    const int r0 = blockIdx.y * 64;
    #pragma unroll
    for (int i = 0; i < 16; ++i) {
        int idx = tid + i*256;
        int r = idx >> 6, c = idx & 63;
        tile[r][c] = in[(size_t)(r0 + r)*C + c0 + c];
    }
    __syncthreads();
    #pragma unroll
    for (int i = 0; i < 16; ++i) {
        int idx = tid + i*256;
        int r = idx >> 6, c = idx & 63;
        out[(size_t)(c0 + r)*R + r0 + c] = f2bf(tile[c][r]);
    }
}

// ---------------------------------------------------------------------------
// Persistent cooperative recurrence:
//   for t in 0..511:  H_{t+1} = tanh(Wxh[X[:,t]] + H_t @ Whh + bh)
// 64 wgs x 256 thr. wg g owns output cols [16g,16g+16); its W_hh^T slice
// ([16 cols][1024 k] bf16 = 32 KB) stays in LDS for all 512 steps.
// Wave w computes rows [16w,16w+16) via 32x mfma_16x16x32_bf16.
// States go to Hst (bf16): slot 0 = H0, slot t+1 = H after step t.
// ---------------------------------------------------------------------------
__global__ __launch_bounds__(256, 1) void k_rnn_persist(
    const unsigned short* __restrict__ WhhT, // [1024 c][1024 k] bf16
    const float* __restrict__ bh,            // [1024]
    const float* __restrict__ Wxh,           // [4096][1024] f32
    const int*   __restrict__ X,             // [64][512]
    const float* __restrict__ H0,            // [64][1024] f32
    unsigned short* __restrict__ Hst,        // [513][64][1024] bf16
    float* __restrict__ Hfin)                // [64][1024] f32 (out tail)
{
    __shared__ unsigned short Wl[16*1024];   // [c][k], XOR-swizzled
    const int tid  = threadIdx.x;
    const int lane = tid & 63;
    const int wave = tid >> 6;               // row-tile 16*wave
    const int g    = blockIdx.x;             // col slice

    // ---- stage W slice into LDS (once), swizzled: byte ^= (c&7)<<4 ----
    #pragma unroll
    for (int it = 0; it < 8; ++it) {
        int slot = it*256 + tid;             // 0..2047 (16B chunks)
        int c  = slot >> 7;                  // 0..15
        int k0 = (slot & 127) * 8;
        short8 v = *(const short8*)&WhhT[(size_t)(g*16 + c)*HID + k0];
        int byte = c*2048 + k0*2;
        byte ^= (c & 7) << 4;
        *(short8*)((char*)Wl + byte) = v;
    }
    // ---- init state slot 0 = bf16(H0) ----
    for (int i = tid; i < 1024; i += 256) {
        int idx = g*1024 + i;
        Hst[idx] = f2bf(H0[idx]);
    }
    __syncthreads();
    cg::grid_group grid = cg::this_grid();
    grid.sync();

    const int col   = g*16 + (lane & 15);
    const float bhc = bh[col];
    const int rowbase = wave*16 + ((lane >> 4) * 4);

    for (int t = 0; t < SEQ; ++t) {
        const unsigned short* Hin = Hst + (size_t)t * HN;
        // prefetch x_t gather early (consumed after the K loop)
        int xi[4];
        #pragma unroll
        for (int q = 0; q < 4; ++q) xi[q] = X[(rowbase + q)*SEQ + t];
        float xv[4];
        #pragma unroll
        for (int q = 0; q < 4; ++q) xv[q] = Wxh[(size_t)xi[q]*HID + col];

        // A fragments: rows 16w+(lane&15), k = ks*32 + (lane>>4)*8
        const unsigned short* arow =
            Hin + (size_t)(wave*16 + (lane & 15))*HID + (lane >> 4)*8;
        short8 af[32];
        #pragma unroll
        for (int ks = 0; ks < 32; ++ks)
            af[ks] = *(const short8*)(arow + ks*32);

        f32x4 acc = (f32x4){0.f, 0.f, 0.f, 0.f};
        #pragma unroll
        for (int ks = 0; ks < 32; ++ks) {
            int byte = (lane & 15)*2048 + ks*64 + (lane >> 4)*16;
            byte ^= (lane & 7) << 4;
            short8 bf = *(const short8*)((char*)Wl + byte);
            acc = __builtin_amdgcn_mfma_f32_16x16x32_bf16(af[ks], bf, acc, 0, 0, 0);
        }

        // epilogue: C row = rowbase+q, col = col
        unsigned short* Hout = Hst + (size_t)(t + 1) * HN;
        #pragma unroll
        for (int q = 0; q < 4; ++q) {
            float h = tanhf(acc[q] + xv[q] + bhc);
            Hout[(size_t)(rowbase + q)*HID + col] = f2bf(h);
            if (t == SEQ - 1) Hfin[(rowbase + q)*HID + col] = h;
        }
        grid.sync();
    }
}

// ---------------------------------------------------------------------------
// Logits GEMM: C[L][4096] = A[L][1024](bf16) * Bt[4096][1024]^T(bf16) + b_q
// 128x128 tile, BK=64, 4 waves (2x2), each wave 64x64 = 4x4 frags 16x16x32
// ---------------------------------------------------------------------------
__global__ __launch_bounds__(256) void k_gemm_logits(
    const unsigned short* __restrict__ A,   // [LROWS][1024] bf16
    const unsigned short* __restrict__ Bt,  // [4096][1024] bf16
    const float* __restrict__ bq,           // [4096]
    float* __restrict__ C)                  // [LROWS][4096]
{
    __shared__ unsigned short lA[128*64];   // row stride 64 bf16 (128B)
    __shared__ unsigned short lB[128*64];
    const int tid  = threadIdx.x;
    const int lane = tid & 63;
    const int wave = tid >> 6;
    const int wm = wave >> 1, wn = wave & 1;
    const int bm = blockIdx.x;
    const int bn = blockIdx.y;
    const int rowA0 = bm * 128;
    const int rowB0 = bn * 128;

    f32x4 acc[4][4];
    #pragma unroll
    for (int i = 0; i < 4; ++i)
        #pragma unroll
        for (int j = 0; j < 4; ++j)
            acc[i][j] = (f32x4){0.f, 0.f, 0.f, 0.f};

    for (int kt = 0; kt < HID; kt += 64) {
        __syncthreads();
        #pragma unroll
        for (int i = 0; i < 4; ++i) {
            int slot = i*256 + tid;          // 16B slots, 8 per tile row
            int row  = slot >> 3;
            int colb = (slot & 7) * 8;       // bf16 col
            const unsigned short* ga = A  + (size_t)(rowA0 + row)*HID + kt + colb;
            const unsigned short* gb = Bt + (size_t)(rowB0 + row)*HID + kt + colb;
            unsigned short* la = lA + (i*256 + (tid >> 6)*64)*8;  // wave-uniform
            unsigned short* lb = lB + (i*256 + (tid >> 6)*64)*8;
            GLL16(ga, la);
            GLL16(gb, lb);
        }
        __syncthreads();
        #pragma unroll
        for (int ks = 0; ks < 2; ++ks) {
            short8 af[4], bf[4];
            #pragma unroll
            for (int i = 0; i < 4; ++i) {
                int row = wm*64 + i*16 + (lane & 15);
                int k   = ks*32 + (lane >> 4)*8;
                af[i] = *(const short8*)&lA[row*64 + k];
            }
            #pragma unroll
            for (int j = 0; j < 4; ++j) {
                int row = wn*64 + j*16 + (lane & 15);
                int k   = ks*32 + (lane >> 4)*8;
                bf[j] = *(const short8*)&lB[row*64 + k];
            }
            #pragma unroll
            for (int i = 0; i < 4; ++i)
                #pragma unroll
                for (int j = 0; j < 4; ++j)
                    acc[i][j] = __builtin_amdgcn_mfma_f32_16x16x32_bf16(af[i], bf[j], acc[i][j], 0, 0, 0);
        }
    }

    // epilogue: D[row=(lane>>4)*4+reg][col=lane&15] per frag, + b_q
    #pragma unroll
    for (int i = 0; i < 4; ++i) {
        int rbase = rowA0 + wm*64 + i*16 + (lane >> 4)*4;
        #pragma unroll
        for (int j = 0; j < 4; ++j) {
            int c = rowB0 + wn*64 + j*16 + (lane & 15);
            float bqv = bq[c];
            #pragma unroll
            for (int reg = 0; reg < 4; ++reg)
                C[(size_t)(rbase + reg)*VOC + c] = acc[i][j][reg] + bqv;
        }
    }
}

// ---------------------------------------------------------------------------
extern "C" void kernel_launch(void* const* d_in, const int* in_sizes, int n_in,
                              void* d_out, int out_size, void* d_ws, size_t ws_size,
                              hipStream_t stream) {
    const int*   X   = (const int*)d_in[0];
    const float* H0  = (const float*)d_in[1];
    const float* Wxh = (const float*)d_in[2];
    const float* Whh = (const float*)d_in[3];
    const float* bh  = (const float*)d_in[4];
    const float* Whq = (const float*)d_in[5];
    const float* bq  = (const float*)d_in[6];
    float* out = (float*)d_out;

    // workspace layout
    char* ws = (char*)d_ws;
    unsigned short* WhhT = (unsigned short*)ws;                       // 2 MB
    unsigned short* BtHq = (unsigned short*)(ws + (size_t)2*1024*1024);   // 8 MB
    unsigned short* Hst  = (unsigned short*)(ws + (size_t)10*1024*1024);  // 513 slots bf16

    k_transpose_f32_bf16<<<dim3(HID/64, HID/64), 256, 0, stream>>>(Whh, WhhT, HID, HID);
    k_transpose_f32_bf16<<<dim3(VOC/64, HID/64), 256, 0, stream>>>(Whq, BtHq, HID, VOC);

    float* Hfin = out + (size_t)LROWS * VOC;
    {
        const unsigned short* a0 = WhhT;
        const float* a1 = bh;
        const float* a2 = Wxh;
        const int*   a3 = X;
        const float* a4 = H0;
        unsigned short* a5 = Hst;
        float* a6 = Hfin;
        void* args[] = { &a0, &a1, &a2, &a3, &a4, &a5, &a6 };
        hipLaunchCooperativeKernel((void*)k_rnn_persist, dim3(64), dim3(256),
                                   args, 0, stream);
    }

    k_gemm_logits<<<dim3(LROWS/128, VOC/128), 256, 0, stream>>>(Hst + HN, BtHq, bq, out);
}

// Round 3
// 4775.961 us; speedup vs baseline: 3.0947x; 1.4421x over previous
//
#include <hip/hip_runtime.h>
#include <hip/hip_bf16.h>
#include <stdint.h>

#define BATCH 64
#define SEQ   512
#define HID   1024
#define VOC   4096
#define LROWS (SEQ*BATCH)   // 32768 output rows
#define HN    (BATCH*HID)   // 65536 elems per H state
#define NWG   64

typedef __attribute__((ext_vector_type(4))) float f32x4;
typedef __attribute__((ext_vector_type(8))) short short8;

__device__ __forceinline__ unsigned short f2bf(float f) {
    unsigned int u = __builtin_bit_cast(unsigned int, f);
    u += 0x7fffu + ((u >> 16) & 1u);   // round-to-nearest-even
    return (unsigned short)(u >> 16);
}

__device__ __forceinline__ float tanh_fast(float x) {
    // |z| stays O(1) here; e^{2x} cannot overflow. rel err ~1e-6.
    float e = __expf(2.f * x);
    return (e - 1.f) * __frcp_rn(e + 1.f);
}

// async global->LDS, 16B per lane, LDS dest = wave-uniform base + lane*16
#define GLL16(g, l) __builtin_amdgcn_global_load_lds( \
    (const __attribute__((address_space(1))) void*)(g), \
    (__attribute__((address_space(3))) void*)(l), 16, 0, 0)

// ---------------------------------------------------------------------------
// Lean device-wide barrier. Monotonic generation; release-only semantics.
// Correctness: all cross-wg data (Hst slots) is write-once-read-once within
// the kernel, and each wg's RELEASE fetch_add flushes its dirty L2 lines to
// the coherent LLC before arrival — so no stale L2 line can exist and no
// acquire-side buffer_inv (L2 invalidate) is needed. Keeps L2 hot.
// ---------------------------------------------------------------------------
__device__ __forceinline__ void gbar(unsigned* cnt, unsigned* flag, unsigned gen) {
    __syncthreads();   // drains vmcnt: all wg stores are at least in L2
    if (threadIdx.x == 0) {
        unsigned old = __hip_atomic_fetch_add(cnt, 1u, __ATOMIC_RELEASE,
                                              __HIP_MEMORY_SCOPE_AGENT);
        if (old == gen * NWG - 1u) {
            __hip_atomic_store(flag, gen, __ATOMIC_RELEASE,
                               __HIP_MEMORY_SCOPE_AGENT);
        } else {
            unsigned f;
            do {
                __builtin_amdgcn_s_sleep(1);
                f = __hip_atomic_load(flag, __ATOMIC_RELAXED,
                                      __HIP_MEMORY_SCOPE_AGENT);
            } while (f < gen);
        }
    }
    __syncthreads();
}

// ---------------------------------------------------------------------------
// Generic: in[R][C] f32  ->  out[C][R] bf16   (transpose + convert)
// ---------------------------------------------------------------------------
__global__ __launch_bounds__(256) void k_transpose_f32_bf16(
    const float* __restrict__ in, unsigned short* __restrict__ out, int R, int C)
{
    __shared__ float tile[64][65];
    const int tid = threadIdx.x;
    const int c0 = blockIdx.x * 64;
    const int r0 = blockIdx.y * 64;
    #pragma unroll
    for (int i = 0; i < 16; ++i) {
        int idx = tid + i*256;
        int r = idx >> 6, c = idx & 63;
        tile[r][c] = in[(size_t)(r0 + r)*C + c0 + c];
    }
    __syncthreads();
    #pragma unroll
    for (int i = 0; i < 16; ++i) {
        int idx = tid + i*256;
        int r = idx >> 6, c = idx & 63;
        out[(size_t)(c0 + r)*R + r0 + c] = f2bf(tile[c][r]);
    }
}

// ---------------------------------------------------------------------------
// Persistent cooperative recurrence with custom barrier.
// 64 wgs x 256 thr; wg g owns output cols [16g,16g+16), W_hh^T slice in LDS.
// ---------------------------------------------------------------------------
__global__ __launch_bounds__(256, 1) void k_rnn_persist(
    const unsigned short* __restrict__ WhhT, // [1024 c][1024 k] bf16
    const float* __restrict__ bh,            // [1024]
    const float* __restrict__ Wxh,           // [4096][1024] f32
    const int*   __restrict__ X,             // [64][512]
    const float* __restrict__ H0,            // [64][1024] f32
    unsigned short* __restrict__ Hst,        // [513][64][1024] bf16
    float* __restrict__ Hfin,                // [64][1024] f32 (out tail)
    unsigned* __restrict__ bar)              // [0]=cnt, [32]=flag (zeroed)
{
    __shared__ unsigned short Wl[16*1024];   // [c][k], XOR-swizzled
    unsigned* cnt  = bar;
    unsigned* flag = bar + 32;
    const int tid  = threadIdx.x;
    const int lane = tid & 63;
    const int wave = tid >> 6;               // row-tile 16*wave
    const int g    = blockIdx.x;             // col slice

    // ---- stage W slice into LDS (once), swizzled: byte ^= (c&7)<<4 ----
    #pragma unroll
    for (int it = 0; it < 8; ++it) {
        int slot = it*256 + tid;             // 0..2047 (16B chunks)
        int c  = slot >> 7;                  // 0..15
        int k0 = (slot & 127) * 8;
        short8 v = *(const short8*)&WhhT[(size_t)(g*16 + c)*HID + k0];
        int byte = c*2048 + k0*2;
        byte ^= (c & 7) << 4;
        *(short8*)((char*)Wl + byte) = v;
    }
    // ---- init state slot 0 = bf16(H0): wg g writes row g ----
    for (int i = tid; i < 1024; i += 256) {
        int idx = g*1024 + i;
        Hst[idx] = f2bf(H0[idx]);
    }

    const int col   = g*16 + (lane & 15);
    const float bhc = bh[col];
    const int rowbase = wave*16 + ((lane >> 4) * 4);

    // prefetch x-gather for t=0 (read-only data, safe before barrier)
    float xv[4];
    #pragma unroll
    for (int q = 0; q < 4; ++q) {
        int xi = X[(rowbase + q)*SEQ + 0];
        xv[q] = Wxh[(size_t)xi*HID + col];
    }

    unsigned gen = 1;
    gbar(cnt, flag, gen++);   // slot 0 visible everywhere

    for (int t = 0; t < SEQ; ++t) {
        const unsigned short* Hin = Hst + (size_t)t * HN;
        // A fragments: rows 16w+(lane&15), k = ks*32 + (lane>>4)*8
        const unsigned short* arow =
            Hin + (size_t)(wave*16 + (lane & 15))*HID + (lane >> 4)*8;
        short8 af[32];
        #pragma unroll
        for (int ks = 0; ks < 32; ++ks)
            af[ks] = __builtin_nontemporal_load((const short8*)(arow + ks*32));

        // prefetch next step's x-gather (H-independent; hides under MFMA)
        float xvn[4] = {0.f, 0.f, 0.f, 0.f};
        if (t + 1 < SEQ) {
            #pragma unroll
            for (int q = 0; q < 4; ++q) {
                int xi = X[(rowbase + q)*SEQ + (t + 1)];
                xvn[q] = Wxh[(size_t)xi*HID + col];
            }
        }

        f32x4 acc = (f32x4){0.f, 0.f, 0.f, 0.f};
        #pragma unroll
        for (int ks = 0; ks < 32; ++ks) {
            int byte = (lane & 15)*2048 + ks*64 + (lane >> 4)*16;
            byte ^= (lane & 7) << 4;
            short8 bf = *(const short8*)((char*)Wl + byte);
            acc = __builtin_amdgcn_mfma_f32_16x16x32_bf16(af[ks], bf, acc, 0, 0, 0);
        }

        unsigned short* Hout = Hst + (size_t)(t + 1) * HN;
        #pragma unroll
        for (int q = 0; q < 4; ++q) {
            float h = tanh_fast(acc[q] + xv[q] + bhc);
            Hout[(size_t)(rowbase + q)*HID + col] = f2bf(h);
            if (t == SEQ - 1) Hfin[(rowbase + q)*HID + col] = h;
        }
        #pragma unroll
        for (int q = 0; q < 4; ++q) xv[q] = xvn[q];

        if (t + 1 < SEQ) gbar(cnt, flag, gen++);   // last step: no barrier needed
    }
}

// ---------------------------------------------------------------------------
// Logits GEMM: C[L][4096] = A[L][1024](bf16) * Bt[4096][1024]^T(bf16) + b_q
// 128x128 tile, BK=64, 4 waves (2x2); XCD-aware block swizzle (8192 % 8 == 0)
// ---------------------------------------------------------------------------
__global__ __launch_bounds__(256) void k_gemm_logits(
    const unsigned short* __restrict__ A,   // [LROWS][1024] bf16
    const unsigned short* __restrict__ Bt,  // [4096][1024] bf16
    const float* __restrict__ bq,           // [4096]
    float* __restrict__ C)                  // [LROWS][4096]
{
    __shared__ unsigned short lA[128*64];   // row stride 64 bf16 (128B)
    __shared__ unsigned short lB[128*64];
    const int tid  = threadIdx.x;
    const int lane = tid & 63;
    const int wave = tid >> 6;
    const int wm = wave >> 1, wn = wave & 1;

    // XCD swizzle: each XCD gets a contiguous chunk of the linear grid
    const int NBM = LROWS/128, NBN = VOC/128;          // 256 x 32 = 8192
    int lid = blockIdx.y * NBM + blockIdx.x;
    int swz = (lid & 7) * (NBM*NBN/8) + (lid >> 3);
    const int bm = swz % NBM;
    const int bn = swz / NBM;
    const int rowA0 = bm * 128;
    const int rowB0 = bn * 128;

    f32x4 acc[4][4];
    #pragma unroll
    for (int i = 0; i < 4; ++i)
        #pragma unroll
        for (int j = 0; j < 4; ++j)
            acc[i][j] = (f32x4){0.f, 0.f, 0.f, 0.f};

    for (int kt = 0; kt < HID; kt += 64) {
        __syncthreads();
        #pragma unroll
        for (int i = 0; i < 4; ++i) {
            int slot = i*256 + tid;          // 16B slots, 8 per tile row
            int row  = slot >> 3;
            int colb = (slot & 7) * 8;       // bf16 col
            const unsigned short* ga = A  + (size_t)(rowA0 + row)*HID + kt + colb;
            const unsigned short* gb = Bt + (size_t)(rowB0 + row)*HID + kt + colb;
            unsigned short* la = lA + (i*256 + (tid >> 6)*64)*8;  // wave-uniform
            unsigned short* lb = lB + (i*256 + (tid >> 6)*64)*8;
            GLL16(ga, la);
            GLL16(gb, lb);
        }
        __syncthreads();
        #pragma unroll
        for (int ks = 0; ks < 2; ++ks) {
            short8 af[4], bf[4];
            #pragma unroll
            for (int i = 0; i < 4; ++i) {
                int row = wm*64 + i*16 + (lane & 15);
                int k   = ks*32 + (lane >> 4)*8;
                af[i] = *(const short8*)&lA[row*64 + k];
            }
            #pragma unroll
            for (int j = 0; j < 4; ++j) {
                int row = wn*64 + j*16 + (lane & 15);
                int k   = ks*32 + (lane >> 4)*8;
                bf[j] = *(const short8*)&lB[row*64 + k];
            }
            #pragma unroll
            for (int i = 0; i < 4; ++i)
                #pragma unroll
                for (int j = 0; j < 4; ++j)
                    acc[i][j] = __builtin_amdgcn_mfma_f32_16x16x32_bf16(af[i], bf[j], acc[i][j], 0, 0, 0);
        }
    }

    // epilogue: D[row=(lane>>4)*4+reg][col=lane&15] per frag, + b_q
    #pragma unroll
    for (int i = 0; i < 4; ++i) {
        int rbase = rowA0 + wm*64 + i*16 + (lane >> 4)*4;
        #pragma unroll
        for (int j = 0; j < 4; ++j) {
            int c = rowB0 + wn*64 + j*16 + (lane & 15);
            float bqv = bq[c];
            #pragma unroll
            for (int reg = 0; reg < 4; ++reg)
                C[(size_t)(rbase + reg)*VOC + c] = acc[i][j][reg] + bqv;
        }
    }
}

// ---------------------------------------------------------------------------
extern "C" void kernel_launch(void* const* d_in, const int* in_sizes, int n_in,
                              void* d_out, int out_size, void* d_ws, size_t ws_size,
                              hipStream_t stream) {
    const int*   X   = (const int*)d_in[0];
    const float* H0  = (const float*)d_in[1];
    const float* Wxh = (const float*)d_in[2];
    const float* Whh = (const float*)d_in[3];
    const float* bh  = (const float*)d_in[4];
    const float* Whq = (const float*)d_in[5];
    const float* bq  = (const float*)d_in[6];
    float* out = (float*)d_out;

    // workspace layout
    char* ws = (char*)d_ws;
    unsigned* bar = (unsigned*)ws;                                        // 1 KB
    unsigned short* WhhT = (unsigned short*)(ws + 1024);                  // 2 MB
    unsigned short* BtHq = (unsigned short*)(ws + 1024 + (size_t)2*1024*1024);   // 8 MB
    unsigned short* Hst  = (unsigned short*)(ws + 1024 + (size_t)10*1024*1024);  // 513 slots bf16

    hipMemsetAsync(bar, 0, 1024, stream);   // barrier state must start at 0 every call

    k_transpose_f32_bf16<<<dim3(HID/64, HID/64), 256, 0, stream>>>(Whh, WhhT, HID, HID);
    k_transpose_f32_bf16<<<dim3(VOC/64, HID/64), 256, 0, stream>>>(Whq, BtHq, HID, VOC);

    float* Hfin = out + (size_t)LROWS * VOC;
    {
        const unsigned short* a0 = WhhT;
        const float* a1 = bh;
        const float* a2 = Wxh;
        const int*   a3 = X;
        const float* a4 = H0;
        unsigned short* a5 = Hst;
        float* a6 = Hfin;
        unsigned* a7 = bar;
        void* args[] = { &a0, &a1, &a2, &a3, &a4, &a5, &a6, &a7 };
        hipLaunchCooperativeKernel((void*)k_rnn_persist, dim3(NWG), dim3(256),
                                   args, 0, stream);
    }

    k_gemm_logits<<<dim3(LROWS/128, VOC/128), 256, 0, stream>>>(Hst + HN, BtHq, bq, out);
}

// Round 4
// 3678.876 us; speedup vs baseline: 4.0176x; 1.2982x over previous
//
#include <hip/hip_runtime.h>
#include <hip/hip_bf16.h>
#include <stdint.h>

#define BATCH 64
#define SEQ   512
#define HID   1024
#define VOC   4096
#define LROWS (SEQ*BATCH)   // 32768 output rows
#define HN    (BATCH*HID)   // 65536 elems per H state
#define NWG   64

typedef __attribute__((ext_vector_type(4))) float f32x4;
typedef __attribute__((ext_vector_type(8))) short short8;

__device__ __forceinline__ unsigned short f2bf(float f) {
    unsigned int u = __builtin_bit_cast(unsigned int, f);
    u += 0x7fffu + ((u >> 16) & 1u);   // round-to-nearest-even
    return (unsigned short)(u >> 16);
}

__device__ __forceinline__ float tanh_fast(float x) {
    // |z| stays O(1) here; e^{2x} cannot overflow. rel err ~1e-6.
    float e = __expf(2.f * x);
    return (e - 1.f) * __frcp_rn(e + 1.f);
}

// Write-through-to-LLC bf16 store: visible device-wide once vmcnt retires.
// (sc0 sc1 = system-scope store; bypasses/writes through the per-XCD L2 so
// no buffer_wbl2 / release fence is ever needed on the step path.)
__device__ __forceinline__ void store_bf16_llc(unsigned short* p, unsigned short v) {
    unsigned int vv = v;
    asm volatile("global_store_short %0, %1, off sc0 sc1" :: "v"(p), "v"(vv) : "memory");
}

// async global->LDS, 16B per lane, LDS dest = wave-uniform base + lane*16
#define GLL16(g, l) __builtin_amdgcn_global_load_lds( \
    (const __attribute__((address_space(1))) void*)(g), \
    (__attribute__((address_space(3))) void*)(l), 16, 0, 0)

// ---------------------------------------------------------------------------
// All-RELAXED device barrier (counter-only, monotonic).
// Writer side: H went out via sc0/sc1 write-through stores; the explicit
// s_waitcnt vmcnt(0) (inline-asm stores are invisible to the compiler's
// s_barrier bookkeeping!) guarantees they are complete at the LLC before this
// wave arrives. Arrival/poll are relaxed 32-bit agent atomics (LLC-coherent).
// No release, no acquire, no wbl2, no buffer_inv -> L2 stays hot.
// Stale-L2 audit: every Hst address is write-once-then-read within a replay;
// across graph replays each XCD's L2 ingests >>4MB (67MB ring + gemm traffic)
// between caching a line and its next-replay reread -> capacity eviction.
// ---------------------------------------------------------------------------
__device__ __forceinline__ void gbar(unsigned* cnt, unsigned target) {
    asm volatile("s_waitcnt vmcnt(0)" ::: "memory");  // drain sc-stores (per wave)
    __syncthreads();
    if (threadIdx.x == 0) {
        __hip_atomic_fetch_add(cnt, 1u, __ATOMIC_RELAXED, __HIP_MEMORY_SCOPE_AGENT);
        unsigned c;
        do {
            __builtin_amdgcn_s_sleep(1);
            c = __hip_atomic_load(cnt, __ATOMIC_RELAXED, __HIP_MEMORY_SCOPE_AGENT);
        } while (c < target);
    }
    __syncthreads();
    asm volatile("" ::: "memory");   // no load hoisting above the spin
}

// ---------------------------------------------------------------------------
// Generic: in[R][C] f32  ->  out[C][R] bf16   (transpose + convert)
// ---------------------------------------------------------------------------
__global__ __launch_bounds__(256) void k_transpose_f32_bf16(
    const float* __restrict__ in, unsigned short* __restrict__ out, int R, int C)
{
    __shared__ float tile[64][65];
    const int tid = threadIdx.x;
    const int c0 = blockIdx.x * 64;
    const int r0 = blockIdx.y * 64;
    #pragma unroll
    for (int i = 0; i < 16; ++i) {
        int idx = tid + i*256;
        int r = idx >> 6, c = idx & 63;
        tile[r][c] = in[(size_t)(r0 + r)*C + c0 + c];
    }
    __syncthreads();
    #pragma unroll
    for (int i = 0; i < 16; ++i) {
        int idx = tid + i*256;
        int r = idx >> 6, c = idx & 63;
        out[(size_t)(c0 + r)*R + r0 + c] = f2bf(tile[c][r]);
    }
}

// ---------------------------------------------------------------------------
// Persistent cooperative recurrence, fence-free sync.
// 64 wgs x 256 thr; wg g owns output cols [16g,16g+16), W_hh^T slice in LDS.
// ---------------------------------------------------------------------------
__global__ __launch_bounds__(256, 1) void k_rnn_persist(
    const unsigned short* __restrict__ WhhT, // [1024 c][1024 k] bf16
    const float* __restrict__ bh,            // [1024]
    const float* __restrict__ Wxh,           // [4096][1024] f32
    const int*   __restrict__ X,             // [64][512]
    const float* __restrict__ H0,            // [64][1024] f32
    unsigned short* __restrict__ Hst,        // [513][64][1024] bf16
    float* __restrict__ Hfin,                // [64][1024] f32 (out tail)
    unsigned* __restrict__ bar)              // [0]=cnt (zeroed per call)
{
    __shared__ unsigned short Wl[16*1024];   // [c][k], XOR-swizzled
    unsigned* cnt  = bar;
    const int tid  = threadIdx.x;
    const int lane = tid & 63;
    const int wave = tid >> 6;               // row-tile 16*wave
    const int g    = blockIdx.x;             // col slice

    // ---- stage W slice into LDS (once), swizzled: byte ^= (c&7)<<4 ----
    #pragma unroll
    for (int it = 0; it < 8; ++it) {
        int slot = it*256 + tid;             // 0..2047 (16B chunks)
        int c  = slot >> 7;                  // 0..15
        int k0 = (slot & 127) * 8;
        short8 v = *(const short8*)&WhhT[(size_t)(g*16 + c)*HID + k0];
        int byte = c*2048 + k0*2;
        byte ^= (c & 7) << 4;
        *(short8*)((char*)Wl + byte) = v;
    }
    // ---- init state slot 0 = bf16(H0): wg g writes batch row g (LLC-visible)
    for (int i = tid; i < 1024; i += 256) {
        int idx = g*1024 + i;
        store_bf16_llc(&Hst[idx], f2bf(H0[idx]));
    }

    const int col   = g*16 + (lane & 15);
    const float bhc = bh[col];
    const int rowbase = wave*16 + ((lane >> 4) * 4);

    // prefetch x-gather for t=0 (read-only data, safe before barrier)
    float xv[4];
    #pragma unroll
    for (int q = 0; q < 4; ++q) {
        int xi = X[(rowbase + q)*SEQ + 0];
        xv[q] = Wxh[(size_t)xi*HID + col];
    }

    unsigned gen = 1;
    gbar(cnt, gen * NWG); gen++;   // slot 0 visible everywhere

    for (int t = 0; t < SEQ; ++t) {
        const unsigned short* Hin = Hst + (size_t)t * HN;
        // A fragments: rows 16w+(lane&15), k = ks*32 + (lane>>4)*8
        // plain loads: L2-shared across the ~8 wgs/XCD (staleness: see gbar)
        const unsigned short* arow =
            Hin + (size_t)(wave*16 + (lane & 15))*HID + (lane >> 4)*8;
        short8 af[32];
        #pragma unroll
        for (int ks = 0; ks < 32; ++ks)
            af[ks] = *(const short8*)(arow + ks*32);

        // prefetch next step's x-gather (H-independent; hides under MFMA)
        float xvn[4] = {0.f, 0.f, 0.f, 0.f};
        if (t + 1 < SEQ) {
            #pragma unroll
            for (int q = 0; q < 4; ++q) {
                int xi = X[(rowbase + q)*SEQ + (t + 1)];
                xvn[q] = Wxh[(size_t)xi*HID + col];
            }
        }

        f32x4 acc = (f32x4){0.f, 0.f, 0.f, 0.f};
        #pragma unroll
        for (int ks = 0; ks < 32; ++ks) {
            int byte = (lane & 15)*2048 + ks*64 + (lane >> 4)*16;
            byte ^= (lane & 7) << 4;
            short8 bf = *(const short8*)((char*)Wl + byte);
            acc = __builtin_amdgcn_mfma_f32_16x16x32_bf16(af[ks], bf, acc, 0, 0, 0);
        }

        unsigned short* Hout = Hst + (size_t)(t + 1) * HN;
        #pragma unroll
        for (int q = 0; q < 4; ++q) {
            float h = tanh_fast(acc[q] + xv[q] + bhc);
            store_bf16_llc(&Hout[(size_t)(rowbase + q)*HID + col], f2bf(h));
            if (t == SEQ - 1) Hfin[(rowbase + q)*HID + col] = h;
        }
        #pragma unroll
        for (int q = 0; q < 4; ++q) xv[q] = xvn[q];

        if (t + 1 < SEQ) { gbar(cnt, gen * NWG); gen++; }  // none after last step
    }
}

// ---------------------------------------------------------------------------
// Logits GEMM: C[L][4096] = A[L][1024](bf16) * Bt[4096][1024]^T(bf16) + b_q
// 128x128 tile, BK=64, 4 waves (2x2); XCD-aware block swizzle (8192 % 8 == 0)
// ---------------------------------------------------------------------------
__global__ __launch_bounds__(256) void k_gemm_logits(
    const unsigned short* __restrict__ A,   // [LROWS][1024] bf16
    const unsigned short* __restrict__ Bt,  // [4096][1024] bf16
    const float* __restrict__ bq,           // [4096]
    float* __restrict__ C)                  // [LROWS][4096]
{
    __shared__ unsigned short lA[128*64];   // row stride 64 bf16 (128B)
    __shared__ unsigned short lB[128*64];
    const int tid  = threadIdx.x;
    const int lane = tid & 63;
    const int wave = tid >> 6;
    const int wm = wave >> 1, wn = wave & 1;

    // XCD swizzle: each XCD gets a contiguous chunk of the linear grid
    const int NBM = LROWS/128, NBN = VOC/128;          // 256 x 32 = 8192
    int lid = blockIdx.y * NBM + blockIdx.x;
    int swz = (lid & 7) * (NBM*NBN/8) + (lid >> 3);
    const int bm = swz % NBM;
    const int bn = swz / NBM;
    const int rowA0 = bm * 128;
    const int rowB0 = bn * 128;

    f32x4 acc[4][4];
    #pragma unroll
    for (int i = 0; i < 4; ++i)
        #pragma unroll
        for (int j = 0; j < 4; ++j)
            acc[i][j] = (f32x4){0.f, 0.f, 0.f, 0.f};

    for (int kt = 0; kt < HID; kt += 64) {
        __syncthreads();
        #pragma unroll
        for (int i = 0; i < 4; ++i) {
            int slot = i*256 + tid;          // 16B slots, 8 per tile row
            int row  = slot >> 3;
            int colb = (slot & 7) * 8;       // bf16 col
            const unsigned short* ga = A  + (size_t)(rowA0 + row)*HID + kt + colb;
            const unsigned short* gb = Bt + (size_t)(rowB0 + row)*HID + kt + colb;
            unsigned short* la = lA + (i*256 + (tid >> 6)*64)*8;  // wave-uniform
            unsigned short* lb = lB + (i*256 + (tid >> 6)*64)*8;
            GLL16(ga, la);
            GLL16(gb, lb);
        }
        __syncthreads();
        #pragma unroll
        for (int ks = 0; ks < 2; ++ks) {
            short8 af[4], bf[4];
            #pragma unroll
            for (int i = 0; i < 4; ++i) {
                int row = wm*64 + i*16 + (lane & 15);
                int k   = ks*32 + (lane >> 4)*8;
                af[i] = *(const short8*)&lA[row*64 + k];
            }
            #pragma unroll
            for (int j = 0; j < 4; ++j) {
                int row = wn*64 + j*16 + (lane & 15);
                int k   = ks*32 + (lane >> 4)*8;
                bf[j] = *(const short8*)&lB[row*64 + k];
            }
            #pragma unroll
            for (int i = 0; i < 4; ++i)
                #pragma unroll
                for (int j = 0; j < 4; ++j)
                    acc[i][j] = __builtin_amdgcn_mfma_f32_16x16x32_bf16(af[i], bf[j], acc[i][j], 0, 0, 0);
        }
    }

    // epilogue: D[row=(lane>>4)*4+reg][col=lane&15] per frag, + b_q
    #pragma unroll
    for (int i = 0; i < 4; ++i) {
        int rbase = rowA0 + wm*64 + i*16 + (lane >> 4)*4;
        #pragma unroll
        for (int j = 0; j < 4; ++j) {
            int c = rowB0 + wn*64 + j*16 + (lane & 15);
            float bqv = bq[c];
            #pragma unroll
            for (int reg = 0; reg < 4; ++reg)
                C[(size_t)(rbase + reg)*VOC + c] = acc[i][j][reg] + bqv;
        }
    }
}

// ---------------------------------------------------------------------------
extern "C" void kernel_launch(void* const* d_in, const int* in_sizes, int n_in,
                              void* d_out, int out_size, void* d_ws, size_t ws_size,
                              hipStream_t stream) {
    const int*   X   = (const int*)d_in[0];
    const float* H0  = (const float*)d_in[1];
    const float* Wxh = (const float*)d_in[2];
    const float* Whh = (const float*)d_in[3];
    const float* bh  = (const float*)d_in[4];
    const float* Whq = (const float*)d_in[5];
    const float* bq  = (const float*)d_in[6];
    float* out = (float*)d_out;

    // workspace layout
    char* ws = (char*)d_ws;
    unsigned* bar = (unsigned*)ws;                                        // 1 KB
    unsigned short* WhhT = (unsigned short*)(ws + 1024);                  // 2 MB
    unsigned short* BtHq = (unsigned short*)(ws + 1024 + (size_t)2*1024*1024);   // 8 MB
    unsigned short* Hst  = (unsigned short*)(ws + 1024 + (size_t)10*1024*1024);  // 513 slots bf16

    hipMemsetAsync(bar, 0, 1024, stream);   // barrier counter must start at 0 every call

    k_transpose_f32_bf16<<<dim3(HID/64, HID/64), 256, 0, stream>>>(Whh, WhhT, HID, HID);
    k_transpose_f32_bf16<<<dim3(VOC/64, HID/64), 256, 0, stream>>>(Whq, BtHq, HID, VOC);

    float* Hfin = out + (size_t)LROWS * VOC;
    {
        const unsigned short* a0 = WhhT;
        const float* a1 = bh;
        const float* a2 = Wxh;
        const int*   a3 = X;
        const float* a4 = H0;
        unsigned short* a5 = Hst;
        float* a6 = Hfin;
        unsigned* a7 = bar;
        void* args[] = { &a0, &a1, &a2, &a3, &a4, &a5, &a6, &a7 };
        hipLaunchCooperativeKernel((void*)k_rnn_persist, dim3(NWG), dim3(256),
                                   args, 0, stream);
    }

    k_gemm_logits<<<dim3(LROWS/128, VOC/128), 256, 0, stream>>>(Hst + HN, BtHq, bq, out);
}